// Round 1
// baseline (2246.731 us; speedup 1.0000x reference)
//
#include <hip/hip_runtime.h>
#include <hip/hip_bf16.h>

// ScatterEdges: out[n,48] = segsum(x*sw, src) - segsum(x*sw, dst)
// E = 1.6M edges, N = 50000 nodes, D = 48 feats (= 12 float4 per edge).
// Edge-parallel, 12 threads per edge each owning one float4 lane of the
// feature vector. Hardware fp32 atomics (unsafeAtomicAdd ->
// global_atomic_add_f32); output (9.6 MB) lives in L2/L3 during the add.

#define THREADS_PER_EDGE 12  // 48 floats / 4 per float4

__global__ void ScatterEdges_kernel(const float4* __restrict__ x,
                                    const float* __restrict__ sw,
                                    const int* __restrict__ src,
                                    const int* __restrict__ dst,
                                    float* __restrict__ out,
                                    int n_edges) {
    int g = blockIdx.x * blockDim.x + threadIdx.x;
    int e = g / THREADS_PER_EDGE;
    int q = g - e * THREADS_PER_EDGE;   // 0..11
    if (e >= n_edges) return;

    float s = sw[e];
    float4 v = x[(size_t)e * THREADS_PER_EDGE + q];
    v.x *= s; v.y *= s; v.z *= s; v.w *= s;

    int si = src[e];
    int di = dst[e];

    float* po = out + (size_t)si * 48 + q * 4;
    unsafeAtomicAdd(po + 0, v.x);
    unsafeAtomicAdd(po + 1, v.y);
    unsafeAtomicAdd(po + 2, v.z);
    unsafeAtomicAdd(po + 3, v.w);

    float* pd = out + (size_t)di * 48 + q * 4;
    unsafeAtomicAdd(pd + 0, -v.x);
    unsafeAtomicAdd(pd + 1, -v.y);
    unsafeAtomicAdd(pd + 2, -v.z);
    unsafeAtomicAdd(pd + 3, -v.w);
}

extern "C" void kernel_launch(void* const* d_in, const int* in_sizes, int n_in,
                              void* d_out, int out_size, void* d_ws, size_t ws_size,
                              hipStream_t stream) {
    const float4* x  = (const float4*)d_in[0];
    const float*  sw = (const float*)d_in[1];
    const int*    src = (const int*)d_in[2];
    const int*    dst = (const int*)d_in[3];
    // d_in[4] (species) only defines N, already encoded in out_size.
    float* out = (float*)d_out;

    int n_edges = in_sizes[1];  // switch has E elements

    // Output is poisoned to 0xAA before every timed launch — zero it.
    hipMemsetAsync(d_out, 0, (size_t)out_size * sizeof(float), stream);

    long long total = (long long)n_edges * THREADS_PER_EDGE;
    int block = 256;
    int grid = (int)((total + block - 1) / block);
    ScatterEdges_kernel<<<grid, block, 0, stream>>>(x, sw, src, dst, out, n_edges);
}

// Round 2
// 917.409 us; speedup vs baseline: 2.4490x; 2.4490x over previous
//
#include <hip/hip_runtime.h>
#include <hip/hip_bf16.h>

// ScatterEdges: out[n,48] = segsum(x*sw, src) - segsum(x*sw, dst)
// E = 1.6M, N = 50000, D = 48.
//
// R1 atomic kernel measured 1940us, bound by atomic op rate (~79G lane-atomics/s,
// WRITE_SIZE 2.4GB for 9.6MB output => 16B RMW per f32 atomic, no combining).
// R2: counting-sort (node -> list of signed edge ids) rebuilt every launch in d_ws,
// then a gather pass: one wave per node, lane = feature, no float atomics at all.

#define D_FEAT 48

// ---------------- CSR build ----------------

__global__ void hist_kernel(const int* __restrict__ src, const int* __restrict__ dst,
                            int* __restrict__ cnt, int E) {
    int e = blockIdx.x * blockDim.x + threadIdx.x;
    if (e >= E) return;
    atomicAdd(&cnt[src[e]], 1);
    atomicAdd(&cnt[dst[e]], 1);
}

// per-256-block exclusive scan of cnt -> offs, block totals -> bsum
__global__ void scan_block(const int* __restrict__ cnt, int* __restrict__ offs,
                           int* __restrict__ bsum, int N) {
    __shared__ int s[256];
    int i = blockIdx.x * 256 + threadIdx.x;
    int v = (i < N) ? cnt[i] : 0;
    s[threadIdx.x] = v;
    __syncthreads();
    for (int d = 1; d < 256; d <<= 1) {
        int t = (threadIdx.x >= (unsigned)d) ? s[threadIdx.x - d] : 0;
        __syncthreads();
        s[threadIdx.x] += t;
        __syncthreads();
    }
    if (i < N) offs[i] = s[threadIdx.x] - v;   // exclusive within block
    if (threadIdx.x == 255) bsum[blockIdx.x] = s[255];
}

// single block: exclusive scan of bsum (any nb, looped in chunks of 256)
__global__ void scan_bsum(int* __restrict__ bsum, int nb) {
    __shared__ int s[256];
    __shared__ int carry;
    if (threadIdx.x == 0) carry = 0;
    __syncthreads();
    for (int base = 0; base < nb; base += 256) {
        int i = base + threadIdx.x;
        int v = (i < nb) ? bsum[i] : 0;
        s[threadIdx.x] = v;
        __syncthreads();
        for (int d = 1; d < 256; d <<= 1) {
            int t = (threadIdx.x >= (unsigned)d) ? s[threadIdx.x - d] : 0;
            __syncthreads();
            s[threadIdx.x] += t;
            __syncthreads();
        }
        if (i < nb) bsum[i] = carry + s[threadIdx.x] - v;
        __syncthreads();
        if (threadIdx.x == 255) carry += s[255];
        __syncthreads();
    }
}

__global__ void add_offs(int* __restrict__ offs, const int* __restrict__ bsum,
                         int* __restrict__ cursor, int N, int total) {
    int i = blockIdx.x * blockDim.x + threadIdx.x;
    if (i < N) {
        int o = offs[i] + bsum[i >> 8];
        offs[i] = o;
        cursor[i] = o;
    }
    if (i == 0) offs[N] = total;
}

__global__ void scatter_kernel(const int* __restrict__ src, const int* __restrict__ dst,
                               int* __restrict__ cursor, int* __restrict__ items, int E) {
    int e = blockIdx.x * blockDim.x + threadIdx.x;
    if (e >= E) return;
    int p = atomicAdd(&cursor[src[e]], 1);
    items[p] = (e << 1);            // +x*sw  (src)
    int q = atomicAdd(&cursor[dst[e]], 1);
    items[q] = (e << 1) | 1;        // -x*sw  (dst)
}

// ---------------- gather ----------------
// one wave per node; lane l (<48) owns feature l. 4-way unrolled for MLP.
__global__ __launch_bounds__(256) void gather_kernel(
        const float* __restrict__ x, const float* __restrict__ sw,
        const int* __restrict__ offs, const int* __restrict__ items,
        float* __restrict__ out, int N) {
    int n = (blockIdx.x * blockDim.x + threadIdx.x) >> 6;   // global wave id
    int lane = threadIdx.x & 63;
    if (n >= N || lane >= D_FEAT) return;

    int start = offs[n];
    int end = offs[n + 1];
    float acc = 0.f;

    int i = start;
    for (; i + 3 < end; i += 4) {
        int it0 = items[i], it1 = items[i + 1], it2 = items[i + 2], it3 = items[i + 3];
        int e0 = it0 >> 1, e1 = it1 >> 1, e2 = it2 >> 1, e3 = it3 >> 1;
        float w0 = sw[e0], w1 = sw[e1], w2 = sw[e2], w3 = sw[e3];
        w0 = (it0 & 1) ? -w0 : w0;
        w1 = (it1 & 1) ? -w1 : w1;
        w2 = (it2 & 1) ? -w2 : w2;
        w3 = (it3 & 1) ? -w3 : w3;
        float v0 = x[(size_t)e0 * D_FEAT + lane];
        float v1 = x[(size_t)e1 * D_FEAT + lane];
        float v2 = x[(size_t)e2 * D_FEAT + lane];
        float v3 = x[(size_t)e3 * D_FEAT + lane];
        acc += w0 * v0;
        acc += w1 * v1;
        acc += w2 * v2;
        acc += w3 * v3;
    }
    for (; i < end; ++i) {
        int it = items[i];
        int e = it >> 1;
        float w = sw[e];
        w = (it & 1) ? -w : w;
        acc += w * x[(size_t)e * D_FEAT + lane];
    }
    out[(size_t)n * D_FEAT + lane] = acc;
}

// ---------------- fallback (R1 atomic path) ----------------

#define THREADS_PER_EDGE 12

__global__ void atomic_fallback_kernel(const float4* __restrict__ x,
                                       const float* __restrict__ sw,
                                       const int* __restrict__ src,
                                       const int* __restrict__ dst,
                                       float* __restrict__ out, int n_edges) {
    int g = blockIdx.x * blockDim.x + threadIdx.x;
    int e = g / THREADS_PER_EDGE;
    int q = g - e * THREADS_PER_EDGE;
    if (e >= n_edges) return;
    float s = sw[e];
    float4 v = x[(size_t)e * THREADS_PER_EDGE + q];
    v.x *= s; v.y *= s; v.z *= s; v.w *= s;
    int si = src[e], di = dst[e];
    float* po = out + (size_t)si * D_FEAT + q * 4;
    unsafeAtomicAdd(po + 0, v.x);
    unsafeAtomicAdd(po + 1, v.y);
    unsafeAtomicAdd(po + 2, v.z);
    unsafeAtomicAdd(po + 3, v.w);
    float* pd = out + (size_t)di * D_FEAT + q * 4;
    unsafeAtomicAdd(pd + 0, -v.x);
    unsafeAtomicAdd(pd + 1, -v.y);
    unsafeAtomicAdd(pd + 2, -v.z);
    unsafeAtomicAdd(pd + 3, -v.w);
}

extern "C" void kernel_launch(void* const* d_in, const int* in_sizes, int n_in,
                              void* d_out, int out_size, void* d_ws, size_t ws_size,
                              hipStream_t stream) {
    const float* x  = (const float*)d_in[0];
    const float* sw = (const float*)d_in[1];
    const int*   src = (const int*)d_in[2];
    const int*   dst = (const int*)d_in[3];
    float* out = (float*)d_out;

    int E = in_sizes[1];   // switch: [E]
    int N = in_sizes[4];   // species: [N]

    // ws layout (ints): cnt[N] | offs[N+1] | cursor[N] | bsum[1024] | items[2E]
    size_t need_ints = (size_t)N + (N + 1) + N + 1024 + 2 * (size_t)E;
    size_t need = need_ints * sizeof(int);

    if (ws_size < need) {
        // fallback: direct atomic scatter (R1 path)
        hipMemsetAsync(d_out, 0, (size_t)out_size * sizeof(float), stream);
        long long total = (long long)E * THREADS_PER_EDGE;
        int block = 256;
        int grid = (int)((total + block - 1) / block);
        atomic_fallback_kernel<<<grid, block, 0, stream>>>(
            (const float4*)x, sw, src, dst, out, E);
        return;
    }

    int* cnt    = (int*)d_ws;
    int* offs   = cnt + N;
    int* cursor = offs + N + 1;
    int* bsum   = cursor + N;
    int* items  = bsum + 1024;

    int nb = (N + 255) / 256;   // scan blocks (196 for N=50000)

    hipMemsetAsync(cnt, 0, (size_t)N * sizeof(int), stream);

    int eblk = (E + 255) / 256;
    hist_kernel<<<eblk, 256, 0, stream>>>(src, dst, cnt, E);
    scan_block<<<nb, 256, 0, stream>>>(cnt, offs, bsum, N);
    scan_bsum<<<1, 256, 0, stream>>>(bsum, nb);
    add_offs<<<nb, 256, 0, stream>>>(offs, bsum, cursor, N, 2 * E);
    scatter_kernel<<<eblk, 256, 0, stream>>>(src, dst, cursor, items, E);

    int gblk = (N + 3) / 4;     // 4 waves (nodes) per 256-thread block
    gather_kernel<<<gblk, 256, 0, stream>>>(x, sw, offs, items, out, N);
}